// Round 1
// baseline (2566.275 us; speedup 1.0000x reference)
//
#include <hip/hip_runtime.h>
#include <hip/hip_bf16.h>
#include <math.h>

#define D_ 1024
#define C_ 512
#define H_ 16
#define DH_ 64
#define P_ 16
#define FF_ 4096
#define S_ 4096
#define B_ 4
#define NC_ 8
#define KP_ 72   // attn LDS pitch (shorts)

typedef __attribute__((ext_vector_type(8))) short short8;
typedef __attribute__((ext_vector_type(4))) float floatx4;

__device__ __forceinline__ float sigmoidf_(float x) { return 1.0f / (1.0f + expf(-x)); }
__device__ __forceinline__ unsigned short f2b(float x) {
    __hip_bfloat16 h = __float2bfloat16(x);
    return __builtin_bit_cast(unsigned short, h);
}
__device__ __forceinline__ float b2f(unsigned short u) {
    __hip_bfloat16 h = __builtin_bit_cast(__hip_bfloat16, u);
    return __bfloat162float(h);
}
// async global->LDS 16B: LDS dst = wave-uniform base + lane*16
__device__ __forceinline__ void async_cp16(const unsigned short* g, short* l) {
    __builtin_amdgcn_global_load_lds(
        (const __attribute__((address_space(1))) void*)g,
        (__attribute__((address_space(3))) void*)l, 16, 0, 0);
}

// ---------------------------------------------------------------- LayerNorm (fp32 in, bf16 out)
__global__ __launch_bounds__(256) void ln_kernel(
    const float* __restrict__ x, long long xBatchStride, int rowsPerBatch,
    const float* __restrict__ add,
    const float* __restrict__ g, const float* __restrict__ beta,
    unsigned short* __restrict__ out)
{
    __shared__ float sbuf[4];
    int row = blockIdx.x;
    int bb = row / rowsPerBatch, s = row - bb * rowsPerBatch;
    const float* xr = x + (long long)bb * xBatchStride + (long long)s * D_;
    int t = threadIdx.x;
    float v[4];
    float4 xv = *(const float4*)(xr + t * 4);
    v[0] = xv.x; v[1] = xv.y; v[2] = xv.z; v[3] = xv.w;
    if (add) {
        float4 av = *(const float4*)(add + (long long)row * D_ + t * 4);
        v[0] += av.x; v[1] += av.y; v[2] += av.z; v[3] += av.w;
    }
    float ls = v[0] + v[1] + v[2] + v[3];
    #pragma unroll
    for (int off = 32; off >= 1; off >>= 1) ls += __shfl_down(ls, off, 64);
    if ((t & 63) == 0) sbuf[t >> 6] = ls;
    __syncthreads();
    float mean = (sbuf[0] + sbuf[1] + sbuf[2] + sbuf[3]) * (1.0f / D_);
    __syncthreads();
    float lv = 0.f;
    #pragma unroll
    for (int i = 0; i < 4; i++) { float d = v[i] - mean; lv += d * d; }
    #pragma unroll
    for (int off = 32; off >= 1; off >>= 1) lv += __shfl_down(lv, off, 64);
    if ((t & 63) == 0) sbuf[t >> 6] = lv;
    __syncthreads();
    float var = (sbuf[0] + sbuf[1] + sbuf[2] + sbuf[3]) * (1.0f / D_);
    float r = rsqrtf(var + 1e-5f);
    unsigned short* orow = out + (long long)row * D_;
    #pragma unroll
    for (int i = 0; i < 4; i++) {
        int c = t * 4 + i;
        orow[c] = f2b((v[i] - mean) * r * g[c] + beta[c]);
    }
}

// ---------------------------------------------------------------- km row L2-normalize (bf16 in-place)
__global__ __launch_bounds__(256) void rownorm_b16(unsigned short* __restrict__ a)
{
    __shared__ float sbuf[4];
    int row = blockIdx.x;
    int t = threadIdx.x;
    unsigned short* ar = a + (long long)row * D_;
    ushort4 xv = *(const ushort4*)(ar + t * 4);
    float v0 = b2f(xv.x), v1 = b2f(xv.y), v2 = b2f(xv.z), v3 = b2f(xv.w);
    float ls = v0 * v0 + v1 * v1 + v2 * v2 + v3 * v3;
    #pragma unroll
    for (int off = 32; off >= 1; off >>= 1) ls += __shfl_down(ls, off, 64);
    if ((t & 63) == 0) sbuf[t >> 6] = ls;
    __syncthreads();
    float ss = sbuf[0] + sbuf[1] + sbuf[2] + sbuf[3];
    float sc = rsqrtf(ss + 1e-6f);
    ushort4 ov;
    ov.x = f2b(v0 * sc); ov.y = f2b(v1 * sc); ov.z = f2b(v2 * sc); ov.w = f2b(v3 * sc);
    *(ushort4*)(ar + t * 4) = ov;
}

// ---------------------------------------------------------------- transposes
__global__ __launch_bounds__(256) void transpose_f32_b16(
    const float* __restrict__ in, unsigned short* __restrict__ out,
    int R, int Cc, long long izs, long long ozs)
{
    __shared__ float tile[32][33];
    int z = blockIdx.z;
    const float* ib = in + (long long)z * izs;
    unsigned short* ob = out + (long long)z * ozs;
    int c0 = blockIdx.x * 32, r0 = blockIdx.y * 32;
    int tx = threadIdx.x & 31, ty = threadIdx.x >> 5;
    #pragma unroll
    for (int i = 0; i < 32; i += 8)
        tile[ty + i][tx] = ib[(long long)(r0 + ty + i) * Cc + c0 + tx];
    __syncthreads();
    #pragma unroll
    for (int i = 0; i < 32; i += 8)
        ob[(long long)(c0 + ty + i) * R + r0 + tx] = f2b(tile[tx][ty + i]);
}

__global__ __launch_bounds__(256) void transpose_b16_b16(
    const unsigned short* __restrict__ in, unsigned short* __restrict__ out,
    int R, int Cc, long long izs, long long ozs)
{
    __shared__ unsigned short tile[32][33];
    int z = blockIdx.z;
    const unsigned short* ib = in + (long long)z * izs;
    unsigned short* ob = out + (long long)z * ozs;
    int c0 = blockIdx.x * 32, r0 = blockIdx.y * 32;
    int tx = threadIdx.x & 31, ty = threadIdx.x >> 5;
    #pragma unroll
    for (int i = 0; i < 32; i += 8)
        tile[ty + i][tx] = ib[(long long)(r0 + ty + i) * Cc + c0 + tx];
    __syncthreads();
    #pragma unroll
    for (int i = 0; i < 32; i += 8)
        ob[(long long)(c0 + ty + i) * R + r0 + tx] = tile[tx][ty + i];
}

// diffT[z][d][t] = bf16(pred[z][t][d] - vm[z][t][d]); strides parameterized
__global__ __launch_bounds__(256) void subT_kernel(
    const float* __restrict__ pred, long long predZs,
    const unsigned short* __restrict__ vm, long long vmZs,
    unsigned short* __restrict__ out, long long outZs)
{
    __shared__ float tile[32][33];
    int z = blockIdx.z;
    int c0 = blockIdx.x * 32, r0 = blockIdx.y * 32;    // c over D, r over C
    int tx = threadIdx.x & 31, ty = threadIdx.x >> 5;
    const float* pb = pred + (long long)z * predZs;
    const unsigned short* vb = vm + (long long)z * vmZs;
    #pragma unroll
    for (int i = 0; i < 32; i += 8) {
        long long idx = (long long)(r0 + ty + i) * D_ + c0 + tx;
        tile[ty + i][tx] = pb[idx] - b2f(vb[idx]);
    }
    __syncthreads();
    unsigned short* ob = out + (long long)z * outZs;
    #pragma unroll
    for (int i = 0; i < 32; i += 8)
        ob[(long long)(c0 + ty + i) * C_ + r0 + tx] = f2b(tile[tx][ty + i]);
}

// ---------------------------------------------------------------- MFMA GEMM engine (m97-style)
// BM=128, BK=32, BN template (128 or 64). 256 thr = 4 waves.
// Staging via global_load_lds 16B: LDS [row][32] shorts, NO padding (required).
// subShift!=0: fused-N col-split; outputs land in contiguous sub-buffers.
// rowsPB!=0: outF/resid mapped as [row/rowsPB]*oBS + (row%rowsPB)*N + col.
template<int BN>
__global__ __launch_bounds__(256) void gemm_flat(
    const unsigned short* __restrict__ A, const unsigned short* __restrict__ BT,
    const float* __restrict__ bias, const float* __restrict__ resid,
    float* __restrict__ outF, unsigned short* __restrict__ outB,
    int K, int N, int subShift, int Mrows, int rowsPB, long long oBS)
{
    constexpr int NJ = BN / 32;
    __shared__ short As[128 * 32];
    __shared__ short Bs[BN * 32];
    int row0 = blockIdx.y * 128, col0 = blockIdx.x * BN;
    int t = threadIdx.x, wave = t >> 6, lane = t & 63;
    int quad = lane >> 4, lo = lane & 15;
    int lrow = lane >> 2, lk = (lane & 3) * 8;
    int wm = (wave & 1) * 64, wn = (wave >> 1) * (BN / 2);
    floatx4 acc[4][NJ];
    #pragma unroll
    for (int i = 0; i < 4; i++)
        #pragma unroll
        for (int j = 0; j < NJ; j++) acc[i][j] = (floatx4){0.f, 0.f, 0.f, 0.f};

    const unsigned short* gA = A + (long long)(row0 + wave * 16 + lrow) * K + lk;
    const unsigned short* gB = BT + (long long)(col0 + wave * 16 + lrow) * K + lk;
    short* lA0 = As + (wave * 16) * 32;
    short* lA1 = As + (64 + wave * 16) * 32;
    short* lB0 = Bs + (wave * 16) * 32;

    for (int k0 = 0; k0 < K; k0 += 32) {
        async_cp16(gA + k0, lA0);
        async_cp16(gA + (long long)64 * K + k0, lA1);
        async_cp16(gB + k0, lB0);
        if (BN == 128) async_cp16(gB + (long long)64 * K + k0, Bs + (64 + wave * 16) * 32);
        __syncthreads();
        short8 a[4], b[NJ];
        #pragma unroll
        for (int i = 0; i < 4; i++) a[i] = *(const short8*)&As[(wm + i * 16 + lo) * 32 + quad * 8];
        #pragma unroll
        for (int j = 0; j < NJ; j++) b[j] = *(const short8*)&Bs[(wn + j * 16 + lo) * 32 + quad * 8];
        #pragma unroll
        for (int i = 0; i < 4; i++)
            #pragma unroll
            for (int j = 0; j < NJ; j++)
                acc[i][j] = __builtin_amdgcn_mfma_f32_16x16x32_bf16(a[i], b[j], acc[i][j], 0, 0, 0);
        __syncthreads();
    }
    #pragma unroll
    for (int i = 0; i < 4; i++)
        #pragma unroll
        for (int j = 0; j < NJ; j++) {
            int col = col0 + wn + j * 16 + lo;
            float bv = bias ? bias[col] : 0.f;
            #pragma unroll
            for (int r = 0; r < 4; r++) {
                int row = row0 + wm + i * 16 + quad * 4 + r;
                long long idx;
                if (subShift)
                    idx = (((long long)(col >> subShift) * Mrows + row) << subShift)
                        + (col & ((1 << subShift) - 1));
                else
                    idx = (long long)row * N + col;
                long long oiF = idx;
                if (rowsPB) {
                    int bb = row / rowsPB, s = row - bb * rowsPB;
                    oiF = (long long)bb * oBS + (long long)s * N + col;
                }
                float v = acc[i][j][r] + bv;
                if (resid) v += resid[oiF];
                if (outF) outF[oiF] = v;
                if (outB) outB[idx] = f2b(v);
            }
        }
}

// z-batched variant. A batch z at A + z*Azs with leading dim lda.
// B batch = z & bmask (ldb = K). fp32 out: z<zsplit -> outF0 + z*Ozs0,
// else outF1 + (z-zsplit)*Ozs1. bf16 out for z < zBcut.
__global__ __launch_bounds__(256) void gemm_batched(
    const unsigned short* __restrict__ A, long long Azs, int lda,
    const unsigned short* __restrict__ BT, long long Bzs, int bmask,
    float* __restrict__ outF0, long long Ozs0,
    float* __restrict__ outF1, long long Ozs1, int zsplit,
    unsigned short* __restrict__ outB, long long OzsB, int zBcut,
    int K, int N)
{
    __shared__ short As[128 * 32];
    __shared__ short Bs[128 * 32];
    int z = blockIdx.z;
    const unsigned short* Ab = A + (long long)z * Azs;
    const unsigned short* Bb = BT + (long long)(z & bmask) * Bzs;
    float* oF = (z < zsplit) ? (outF0 + (long long)z * Ozs0)
                             : (outF1 + (long long)(z - zsplit) * Ozs1);
    unsigned short* oB = (outB && z < zBcut) ? outB + (long long)z * OzsB : nullptr;
    int row0 = blockIdx.y * 128, col0 = blockIdx.x * 128;
    int t = threadIdx.x, wave = t >> 6, lane = t & 63;
    int quad = lane >> 4, lo = lane & 15;
    int lrow = lane >> 2, lk = (lane & 3) * 8;
    int wm = (wave & 1) * 64, wn = (wave >> 1) * 64;
    floatx4 acc[4][4];
    #pragma unroll
    for (int i = 0; i < 4; i++)
        #pragma unroll
        for (int j = 0; j < 4; j++) acc[i][j] = (floatx4){0.f, 0.f, 0.f, 0.f};

    const unsigned short* gA = Ab + (long long)(row0 + wave * 16 + lrow) * lda + lk;
    const unsigned short* gB = Bb + (long long)(col0 + wave * 16 + lrow) * K + lk;
    short* lA0 = As + (wave * 16) * 32;
    short* lA1 = As + (64 + wave * 16) * 32;
    short* lB0 = Bs + (wave * 16) * 32;
    short* lB1 = Bs + (64 + wave * 16) * 32;

    for (int k0 = 0; k0 < K; k0 += 32) {
        async_cp16(gA + k0, lA0);
        async_cp16(gA + 64LL * lda + k0, lA1);
        async_cp16(gB + k0, lB0);
        async_cp16(gB + 64LL * K + k0, lB1);
        __syncthreads();
        short8 a[4], b[4];
        #pragma unroll
        for (int i = 0; i < 4; i++) a[i] = *(const short8*)&As[(wm + i * 16 + lo) * 32 + quad * 8];
        #pragma unroll
        for (int j = 0; j < 4; j++) b[j] = *(const short8*)&Bs[(wn + j * 16 + lo) * 32 + quad * 8];
        #pragma unroll
        for (int i = 0; i < 4; i++)
            #pragma unroll
            for (int j = 0; j < 4; j++)
                acc[i][j] = __builtin_amdgcn_mfma_f32_16x16x32_bf16(a[i], b[j], acc[i][j], 0, 0, 0);
        __syncthreads();
    }
    #pragma unroll
    for (int i = 0; i < 4; i++)
        #pragma unroll
        for (int j = 0; j < 4; j++) {
            int col = col0 + wn + j * 16 + lo;
            #pragma unroll
            for (int r = 0; r < 4; r++) {
                int row = row0 + wm + i * 16 + quad * 4 + r;
                long long idx = (long long)row * N + col;
                float v = acc[i][j][r];
                if (oF) oF[idx] = v;
                if (oB) oB[idx] = f2b(v);
            }
        }
}

// ---------------------------------------------------------------- momentum update fused with M^T->bf16
// St = eta*St - theta*grad; M = (1-alpha)*M + St; Mt[z][c][r] = bf16(M[z][r][c])
__global__ __launch_bounds__(256) void update_mem_t(
    float* __restrict__ M, float* __restrict__ St, const float* __restrict__ grad,
    unsigned short* __restrict__ Mt,
    const float* __restrict__ lr, const float* __restrict__ mom, const float* __restrict__ fg)
{
    __shared__ float tile[32][33];
    int z = blockIdx.z;
    int c0 = blockIdx.x * 32, r0 = blockIdx.y * 32;
    int tx = threadIdx.x & 31, ty = threadIdx.x >> 5;
    float theta = sigmoidf_(lr[0]) * (1.0f / C_);
    float eta   = sigmoidf_(mom[0]);
    float alpha = sigmoidf_(fg[0]);
    long long zb = (long long)z * D_ * D_;
    #pragma unroll
    for (int i = 0; i < 32; i += 8) {
        long long idx = zb + (long long)(r0 + ty + i) * D_ + c0 + tx;
        float st = eta * St[idx] - theta * grad[idx];
        St[idx] = st;
        float m = (1.0f - alpha) * M[idx] + st;
        M[idx] = m;
        tile[ty + i][tx] = m;
    }
    __syncthreads();
    #pragma unroll
    for (int i = 0; i < 32; i += 8)
        Mt[zb + (long long)(c0 + ty + i) * D_ + r0 + tx] = f2b(tile[tx][ty + i]);
}

// ---------------------------------------------------------------- gated combine (group-batched)
__global__ __launch_bounds__(256) void gate_combine_kernel(
    const float* __restrict__ x, long long xBS,
    const float* __restrict__ gbuf, const float* __restrict__ aoW,
    const float* __restrict__ mctx, float* __restrict__ o, long long oBS,
    int gcShift, long long n)
{
    long long i = (long long)blockIdx.x * 256 + threadIdx.x;
    if (i >= n) return;
    int row = (int)(i >> 10);
    int c = (int)(i & 1023);
    int bb = row >> gcShift, s = row & ((1 << gcShift) - 1);
    float g = sigmoidf_(gbuf[i]);
    float xv = x[(long long)bb * xBS + (long long)s * D_ + c];
    o[(long long)bb * oBS + (long long)s * D_ + c] = xv + g * aoW[i] + (1.0f - g) * mctx[i];
}

__global__ __launch_bounds__(256) void silu_mul_b16(
    unsigned short* __restrict__ a, const unsigned short* __restrict__ b, long long n8)
{
    long long i = (long long)blockIdx.x * 256 + threadIdx.x;
    if (i >= n8) return;
    int4 av = ((const int4*)a)[i];
    int4 bv = ((const int4*)b)[i];
    unsigned short* ap = (unsigned short*)&av;
    const unsigned short* bp = (const unsigned short*)&bv;
    #pragma unroll
    for (int j = 0; j < 8; j++) {
        float x = b2f(ap[j]);
        float y = b2f(bp[j]);
        ap[j] = f2b((x / (1.0f + expf(-x))) * y);
    }
    ((int4*)a)[i] = av;
}

// ---------------------------------------------------------------- MFMA flash attention (group-batched)
// Rows are group-local: token index in [0, GC). Causality is per-C_-chunk:
// q at group-local q0 attends persistent tokens + keys in [q0 & ~(C_-1), q0+...].
__global__ __launch_bounds__(256) void attn_mfma(
    const unsigned short* __restrict__ qh, const unsigned short* __restrict__ kh,
    const unsigned short* __restrict__ vh,
    const float* __restrict__ pk, const float* __restrict__ pv,
    unsigned short* __restrict__ ao, int GC)
{
    __shared__ __align__(16) short Ks[64][KP_];
    __shared__ __align__(16) short Vs[64][KP_];
    __shared__ __align__(16) short Ps[4][16][KP_];
    int qb = blockIdx.x, h = blockIdx.y, b = blockIdx.z;
    int q0 = qb * 64;
    int kbase = q0 & ~(C_ - 1);
    int t = threadIdx.x;
    int wave = t >> 6, lane = t & 63;
    int quad = lane >> 4, lo = lane & 15;

    short8 qf[2];
    {
        const unsigned short* qp = qh + (long long)(b * GC + q0 + wave * 16 + lo) * (H_ * DH_)
                                   + h * DH_ + quad * 8;
        qf[0] = *(const short8*)qp;
        qf[1] = *(const short8*)(qp + 32);
    }
    floatx4 o4[4];
    #pragma unroll
    for (int dt = 0; dt < 4; dt++) o4[dt] = (floatx4){0.f, 0.f, 0.f, 0.f};
    float m[4], l[4];
    #pragma unroll
    for (int r = 0; r < 4; r++) { m[r] = -1e30f; l[r] = 0.f; }
    {
        short* pz = &Ps[wave][lo][16 + quad * 4];
        pz[0] = 0; pz[1] = 0; pz[2] = 0; pz[3] = 0;
    }

    int ktmax = ((q0 - kbase) >> 6) + 1;
    for (int kt = 0; kt <= ktmax; kt++) {
        __syncthreads();
        if (kt == 0) {
            int key = t >> 4, d4 = (t & 15) * 4;
            float4 kv4 = *(const float4*)(pk + ((long long)key * H_ + h) * DH_ + d4);
            Ks[key][d4 + 0] = f2b(kv4.x); Ks[key][d4 + 1] = f2b(kv4.y);
            Ks[key][d4 + 2] = f2b(kv4.z); Ks[key][d4 + 3] = f2b(kv4.w);
            float4 vv4 = *(const float4*)(pv + ((long long)key * H_ + h) * DH_ + d4);
            Vs[d4 + 0][key] = f2b(vv4.x); Vs[d4 + 1][key] = f2b(vv4.y);
            Vs[d4 + 2][key] = f2b(vv4.z); Vs[d4 + 3][key] = f2b(vv4.w);
            int dz = t >> 2, kz = 16 + (t & 3) * 4;
            Vs[dz][kz + 0] = 0; Vs[dz][kz + 1] = 0;
            Vs[dz][kz + 2] = 0; Vs[dz][kz + 3] = 0;
        } else {
            int tok0 = kbase + (kt - 1) * 64;
            {
                int key = t >> 2, dblk = (t & 3) * 16;
                const unsigned short* kp2 = kh + (long long)(b * GC + tok0 + key) * (H_ * DH_)
                                            + h * DH_ + dblk;
                *(short8*)&Ks[key][dblk]     = *(const short8*)kp2;
                *(short8*)&Ks[key][dblk + 8] = *(const short8*)(kp2 + 8);
            }
            {
                int kp = t & 31, dg = t >> 5;
                const unsigned short* vp0 = vh + (long long)(b * GC + tok0 + 2 * kp) * (H_ * DH_)
                                            + h * DH_ + dg * 8;
                short8 v0 = *(const short8*)vp0;
                short8 v1 = *(const short8*)(vp0 + H_ * DH_);
                #pragma unroll
                for (int j = 0; j < 8; j++) {
                    unsigned int pk2 = ((unsigned int)(unsigned short)v1[j] << 16)
                                     | (unsigned short)v0[j];
                    *(unsigned int*)&Vs[dg * 8 + j][2 * kp] = pk2;
                }
            }
        }
        __syncthreads();

        int ntiles = (kt == 0) ? 1 : 4;
        floatx4 s4[4];
        #pragma unroll
        for (int nt = 0; nt < 4; nt++) {
            if (nt >= ntiles) break;
            s4[nt] = (floatx4){0.f, 0.f, 0.f, 0.f};
            #pragma unroll
            for (int ks = 0; ks < 2; ks++) {
                short8 bf = *(const short8*)&Ks[nt * 16 + lo][ks * 32 + quad * 8];
                s4[nt] = __builtin_amdgcn_mfma_f32_16x16x32_bf16(qf[ks], bf, s4[nt], 0, 0, 0);
            }
        }
        bool diag = (kt == ktmax);
        int key0 = kbase + (kt - 1) * 64;
        #pragma unroll
        for (int nt = 0; nt < 4; nt++) {
            if (nt >= ntiles) break;
            #pragma unroll
            for (int r = 0; r < 4; r++) {
                float v = s4[nt][r] * 0.125f;
                if (diag) {
                    int kg = key0 + nt * 16 + lo;
                    int qq = q0 + wave * 16 + quad * 4 + r;
                    if (kg > qq) v = -1e30f;
                }
                s4[nt][r] = v;
            }
        }
        float alpha[4];
        #pragma unroll
        for (int r = 0; r < 4; r++) {
            float tm = s4[0][r];
            #pragma unroll
            for (int nt = 1; nt < 4; nt++) { if (nt >= ntiles) break; tm = fmaxf(tm, s4[nt][r]); }
            #pragma unroll
            for (int msk = 1; msk <= 8; msk <<= 1) tm = fmaxf(tm, __shfl_xor(tm, msk, 64));
            float mn = fmaxf(m[r], tm);
            alpha[r] = __expf(m[r] - mn);
            float sum = 0.f;
            #pragma unroll
            for (int nt = 0; nt < 4; nt++) {
                if (nt >= ntiles) break;
                float p = __expf(s4[nt][r] - mn);
                sum += p;
                Ps[wave][quad * 4 + r][nt * 16 + lo] = f2b(p);
            }
            #pragma unroll
            for (int msk = 1; msk <= 8; msk <<= 1) sum += __shfl_xor(sum, msk, 64);
            l[r] = l[r] * alpha[r] + sum;
            m[r] = mn;
        }
        #pragma unroll
        for (int dt = 0; dt < 4; dt++)
            #pragma unroll
            for (int r = 0; r < 4; r++) o4[dt][r] *= alpha[r];
        __syncthreads();
        int ksteps = (kt == 0) ? 1 : 2;
        #pragma unroll
        for (int ks = 0; ks < 2; ks++) {
            if (ks >= ksteps) break;
            short8 af = *(const short8*)&Ps[wave][lo][ks * 32 + quad * 8];
            #pragma unroll
            for (int dt = 0; dt < 4; dt++) {
                short8 bf = *(const short8*)&Vs[dt * 16 + lo][ks * 32 + quad * 8];
                o4[dt] = __builtin_amdgcn_mfma_f32_16x16x32_bf16(af, bf, o4[dt], 0, 0, 0);
            }
        }
    }
    #pragma unroll
    for (int r = 0; r < 4; r++) {
        float inv = 1.0f / l[r];
        int q = q0 + wave * 16 + quad * 4 + r;
        unsigned short* aop = ao + (long long)(b * GC + q) * (H_ * DH_) + h * DH_ + lo;
        #pragma unroll
        for (int dt = 0; dt < 4; dt++) aop[dt * 16] = f2b(o4[dt][r] * inv);
    }
}

// ---------------------------------------------------------------- launch
extern "C" void kernel_launch(void* const* d_in, const int* in_sizes, int n_in,
                              void* d_out, int out_size, void* d_ws, size_t ws_size,
                              hipStream_t stream)
{
    const float* x     = (const float*)d_in[0];
    const float* g1    = (const float*)d_in[1];
    const float* b1    = (const float*)d_in[2];
    const float* g2    = (const float*)d_in[3];
    const float* b2    = (const float*)d_in[4];
    const float* g3    = (const float*)d_in[5];
    const float* b3    = (const float*)d_in[6];
    const float* Wqm   = (const float*)d_in[7];
    const float* Wkm   = (const float*)d_in[8];
    const float* Wvm   = (const float*)d_in[9];
    const float* lr    = (const float*)d_in[10];
    const float* mom   = (const float*)d_in[11];
    const float* fg    = (const float*)d_in[12];
    const float* Wq    = (const float*)d_in[13];
    const float* bq    = (const float*)d_in[14];
    const float* Wk    = (const float*)d_in[15];
    const float* bk    = (const float*)d_in[16];
    const float* Wv    = (const float*)d_in[17];
    const float* bv    = (const float*)d_in[18];
    const float* Wo    = (const float*)d_in[19];
    const float* bo    = (const float*)d_in[20];
    const float* pk    = (const float*)d_in[21];
    const float* pv    = (const float*)d_in[22];
    const float* Wg    = (const float*)d_in[23];
    const float* bg    = (const float*)d_in[24];
    const float* Wgate = (const float*)d_in[25];
    const float* bgate = (const float*)d_in[26];
    const float* Wup   = (const float*)d_in[27];
    const float* bup   = (const float*)d_in[28];
    const float* Wdown = (const float*)d_in[29];
    const float* bdown = (const float*)d_in[30];
    float* out = (float*)d_out;

    const long long MiB = 1024LL * 1024LL;
    char* w = (char*)d_ws;
    // ---- fixed region [0, 109 MiB)
    float* M   = (float*)(w + 0 * MiB);                         // 16
    float* St  = (float*)(w + 16 * MiB);                        // 16
    unsigned short* Mt     = (unsigned short*)(w + 32 * MiB);   // 8 (bf16 M^T, produced by update)
    unsigned short* WqkvmT = (unsigned short*)(w + 40 * MiB);   // 6 [3072][1024]
    unsigned short* WqkvhT = (unsigned short*)(w + 46 * MiB);   // 6
    unsigned short* WoT    = (unsigned short*)(w + 52 * MiB);   // 2
    unsigned short* WgT    = (unsigned short*)(w + 54 * MiB);   // 2
    unsigned short* WffT   = (unsigned short*)(w + 56 * MiB);   // 16 [8192][1024]
    unsigned short* WdownT = (unsigned short*)(w + 72 * MiB);   // 8 [1024][4096]
    float* bqkvh = (float*)(w + 80 * MiB);                      // 12 KB
    float* bff   = (float*)(w + 80 * MiB + 65536);              // 32 KB
    float* F3 = (float*)(w + 81 * MiB);                         // pred fp32, 8
    float* Fg = (float*)(w + 89 * MiB);                         // grad fp32, 16
    unsigned short* diffT = (unsigned short*)(w + 105 * MiB);   // 4
    char* gbase = w + 109 * MiB;

    // ---- group size selection: need 109 + 48*G MiB (G ∈ {8,4,2,1}); tight G=1 needs 141
    int G = 8;
    while (G > 1 && (size_t)((109 + 48 * G) * MiB) > ws_size) G >>= 1;
    bool tight = ((size_t)((109 + 48 * G) * MiB) > ws_size);  // only reachable at G==1
    const int GC = G * C_;
    const int NG = NC_ / G;
    const int RG = B_ * GC;
    int gcShift = 0; while ((1 << gcShift) < GC) gcShift++;
    const long long GiM = (long long)G * MiB;

    // ---- group region (sizes in G·MiB): S1 QKVm/HQ 12 | S2 kmT/Hao 4 | S3 mctx32 8 |
    //      S4 mctx16 4 | aoW 8 | g 8 | LNout 4.  G0G1 (32G) overlays S1..aoW-half
    //      (all dead by FFN time). Tight: aoW=F3, g=Fg, G0G1 overlays diffT..S4.
    unsigned short* QKVm  = (unsigned short*)(gbase);                // also HQ (qh|kh|vh)
    unsigned short* kmTG  = (unsigned short*)(gbase + 12 * GiM);     // also Hao
    float* mctx32         = (float*)(gbase + 16 * GiM);
    unsigned short* mctx16 = (unsigned short*)(gbase + 24 * GiM);
    float* aoW; float* gG; unsigned short* LNout; unsigned short* G0;
    if (!tight) {
        aoW   = (float*)(gbase + 28 * GiM);
        gG    = (float*)(gbase + 36 * GiM);
        LNout = (unsigned short*)(gbase + 44 * GiM);
        G0    = (unsigned short*)gbase;
    } else {
        aoW   = F3;            // 8 MiB, dead during tail
        gG    = Fg;            // 16 MiB, dead during tail
        LNout = (unsigned short*)(gbase + 28 * MiB);
        G0    = (unsigned short*)(w + 105 * MiB);  // diffT..S4 = 32 MiB contiguous
    }

    hipMemsetAsync(d_ws, 0, (size_t)(40 * MiB), stream);   // zero M, St, Mt

    // concat biases
    hipMemcpyAsync(bqkvh,        bq,    4096,  hipMemcpyDeviceToDevice, stream);
    hipMemcpyAsync(bqkvh + 1024, bk,    4096,  hipMemcpyDeviceToDevice, stream);
    hipMemcpyAsync(bqkvh + 2048, bv,    4096,  hipMemcpyDeviceToDevice, stream);
    hipMemcpyAsync(bff,          bgate, 16384, hipMemcpyDeviceToDevice, stream);
    hipMemcpyAsync(bff + 4096,   bup,   16384, hipMemcpyDeviceToDevice, stream);

    // weight transposes -> bf16 [N][K]
    transpose_f32_b16<<<dim3(32, 32, 1), 256, 0, stream>>>(Wqm, WqkvmT,            D_, D_, 0, 0);
    transpose_f32_b16<<<dim3(32, 32, 1), 256, 0, stream>>>(Wkm, WqkvmT + 1048576,  D_, D_, 0, 0);
    transpose_f32_b16<<<dim3(32, 32, 1), 256, 0, stream>>>(Wvm, WqkvmT + 2097152,  D_, D_, 0, 0);
    transpose_f32_b16<<<dim3(32, 32, 1), 256, 0, stream>>>(Wq,  WqkvhT,            D_, D_, 0, 0);
    transpose_f32_b16<<<dim3(32, 32, 1), 256, 0, stream>>>(Wk,  WqkvhT + 1048576,  D_, D_, 0, 0);
    transpose_f32_b16<<<dim3(32, 32, 1), 256, 0, stream>>>(Wv,  WqkvhT + 2097152,  D_, D_, 0, 0);
    transpose_f32_b16<<<dim3(32, 32, 1), 256, 0, stream>>>(Wo,  WoT,               D_, D_, 0, 0);
    transpose_f32_b16<<<dim3(32, 32, 1), 256, 0, stream>>>(Wg,  WgT,               D_, D_, 0, 0);
    transpose_f32_b16<<<dim3(128, 32, 1), 256, 0, stream>>>(Wgate, WffT,           D_, FF_, 0, 0);
    transpose_f32_b16<<<dim3(128, 32, 1), 256, 0, stream>>>(Wup,   WffT + 4194304, D_, FF_, 0, 0);
    transpose_f32_b16<<<dim3(32, 128, 1), 256, 0, stream>>>(Wdown, WdownT,         FF_, D_, 0, 0);

    const long long xBS = (long long)S_ * D_;

    for (int g = 0; g < NG; g++) {
        const float* xg = x   + (long long)g * GC * D_;   // rows (b, g*GC + s')
        float* og       = out + (long long)g * GC * D_;

        // A) h1 = LN1(x) for the whole group -> LNout
        ln_kernel<<<RG, 256, 0, stream>>>(xg, xBS, GC, nullptr, g1, b1, LNout);
        // B) qm|km|vm for the whole group -> QKVm (col-split slots of RG x 1024)
        gemm_flat<128><<<dim3(24, RG / 128), 256, 0, stream>>>(LNout, WqkvmT, nullptr, nullptr,
            nullptr, QKVm, D_, 3072, 10, RG, 0, 0);
        // C) km L2-normalize; km^T per batch -> kmTG [b][1024][GC]
        rownorm_b16<<<RG, 256, 0, stream>>>(QKVm + (long long)RG * D_);
        transpose_b16_b16<<<dim3(32, GC / 32, 4), 256, 0, stream>>>(QKVm + (long long)RG * D_,
            kmTG, GC, D_, (long long)GC * D_, (long long)D_ * GC);

        // D) serial memory recurrence, chunk by chunk
        for (int j = 0; j < G; j++) {
            // mem_ctx (z=0..3, qm@Mt) + pred (z=4..7, km@Mt). z*GC*D lands on the km
            // slot exactly at z=4 since slot size = 4*GC*D.
            gemm_batched<<<dim3(8, 4, 8), 256, 0, stream>>>(
                QKVm + (long long)j * C_ * D_, (long long)GC * D_, D_,
                Mt, (long long)D_ * D_, 3,
                mctx32 + (long long)j * C_ * D_, (long long)GC * D_,
                F3, (long long)C_ * D_, 4,
                mctx16 + (long long)j * C_ * D_, (long long)GC * D_, 4,
                D_, D_);
            // diffT = (pred - vm)^T
            subT_kernel<<<dim3(32, 16, 4), 256, 0, stream>>>(
                F3, (long long)C_ * D_,
                QKVm + 2LL * RG * D_ + (long long)j * C_ * D_, (long long)GC * D_,
                diffT, (long long)D_ * C_);
            // grad = km^T @ diffT^T
            gemm_batched<<<dim3(8, 8, 4), 256, 0, stream>>>(
                kmTG + (long long)j * C_, (long long)D_ * GC, GC,
                diffT, (long long)D_ * C_, 3,
                Fg, (long long)D_ * D_, nullptr, 0, 8,
                nullptr, 0, 0, C_, D_);
            // momentum + forget update; writes Mt (bf16 M^T) for the next chunk
            update_mem_t<<<dim3(32, 32, 4), 256, 0, stream>>>(M, St, Fg, Mt, lr, mom, fg);
        }

        // E) h2 = LN2(x + mem_ctx) -> LNout
        ln_kernel<<<RG, 256, 0, stream>>>(xg, xBS, GC, mctx32, g2, b2, LNout);
        // F) qh|kh|vh -> QKVm (HQ role)
        gemm_flat<128><<<dim3(24, RG / 128), 256, 0, stream>>>(LNout, WqkvhT, bqkvh, nullptr,
            nullptr, QKVm, D_, 3072, 10, RG, 0, 0);
        // G) attention (per-chunk causal inside the group) -> Hao (kmTG region)
        attn_mfma<<<dim3(GC / 64, H_, B_), 256, 0, stream>>>(QKVm, QKVm + (long long)RG * D_,
            QKVm + 2LL * RG * D_, pk, pv, kmTG, GC);
        // H) aoW = ao @ Wo + bo -> aoW fp32
        gemm_flat<64><<<dim3(16, RG / 128), 256, 0, stream>>>(kmTG, WoT, bo, nullptr,
            aoW, nullptr, D_, D_, 0, 0, 0, 0);
        // I) gbuf = mem_ctx @ Wg + bg -> gG fp32
        gemm_flat<64><<<dim3(16, RG / 128), 256, 0, stream>>>(mctx16, WgT, bg, nullptr,
            gG, nullptr, D_, D_, 0, 0, 0, 0);
        // J) o = x + sig(g)*aoW + (1-sig)*mem_ctx -> out (in place of final layout)
        gate_combine_kernel<<<(int)(((long long)RG * D_) / 256), 256, 0, stream>>>(
            xg, xBS, gG, aoW, mctx32, og, xBS, gcShift, (long long)RG * D_);
        // K) h3 = LN3(o) -> LNout
        ln_kernel<<<RG, 256, 0, stream>>>(og, xBS, GC, nullptr, g3, b3, LNout);
        // L) gate|up -> G0|G1 (col-split slots of RG x 4096)
        gemm_flat<128><<<dim3(64, RG / 128), 256, 0, stream>>>(LNout, WffT, bff, nullptr,
            nullptr, G0, D_, 8192, 12, RG, 0, 0);
        // M) G0 <- silu(G0)*G1
        silu_mul_b16<<<(int)(((long long)RG * FF_ / 8) / 256), 256, 0, stream>>>(
            G0, G0 + (long long)RG * FF_, (long long)RG * FF_ / 8);
        // N) out = o + prod @ Wdown + bdown (resid read from out with same mapping)
        gemm_flat<64><<<dim3(16, RG / 128), 256, 0, stream>>>(G0, WdownT, bdown, og,
            og, nullptr, FF_, D_, 0, 0, GC, xBS);
    }
}